// Round 10
// baseline (11651.537 us; speedup 1.0000x reference)
//
#include <hip/hip_runtime.h>
#include <hip/hip_fp16.h>

// ReviewAnalyzeModel: 2-layer biLSTM, B=64 T=512 E=256 H=256, V=50000.
// prep(cvt fp16) -> GEMM proj0 -> scan0 -> GEMM proj1 -> scan1 -> final linear.
// Scan R10: 4 blocks x 512 thr. block = (dir, j-half); each block runs ALL 4
// batch-slices (independent scans, SHARED weights) round-robin per step, so the
// cross-L2 sync RTT of one slice hides under compute of the other three.
// Per-slice protocol identical to R9 (proven): tid0 relaxed-poll + one acquire +
// barrier broadcast; stores -> barrier -> tid0 release-store. Own j-half h via
// LDS; peer half via global ring (= h0, slot t+1, guards 0/513).

typedef _Float16 f16;
typedef _Float16 half8 __attribute__((ext_vector_type(8)));
typedef float floatx4 __attribute__((ext_vector_type(4)));

#if __has_builtin(__builtin_amdgcn_global_load_lds)
#define HAS_GLL 1
#endif

#if __has_builtin(__builtin_amdgcn_exp2f)
#define EXP2F __builtin_amdgcn_exp2f
#else
#define EXP2F exp2f
#endif
#if __has_builtin(__builtin_amdgcn_rcpf)
#define RCPF __builtin_amdgcn_rcpf
#else
#define RCPF(x) (1.0f/(x))
#endif

__device__ __forceinline__ float sigf(float x) {
  return RCPF(1.f + EXP2F(-1.4426950408889634f * x));
}
__device__ __forceinline__ float tanhf_(float x) {
  return 2.f * RCPF(1.f + EXP2F(-2.8853900817779268f * x)) - 1.f;
}

// ---------------- prep kernels ----------------

__global__ void k_cvt_embed(const float* __restrict__ src, f16* __restrict__ dst, int n8) {
  int i = blockIdx.x * blockDim.x + threadIdx.x;
  if (i >= n8) return;
  const float4* s = (const float4*)(src + (size_t)i * 8);
  float4 a = s[0], b = s[1];
  half8 h = { (f16)a.x,(f16)a.y,(f16)a.z,(f16)a.w,(f16)b.x,(f16)b.y,(f16)b.z,(f16)b.w };
  *(half8*)(dst + (size_t)i * 8) = h;
}

// dst[n'][k], n' = d*1024 + j*4 + gate ; src row (gate*256+j) of Wih_l?_{f,b}
__global__ void k_cvt_wih(const float* __restrict__ sf, const float* __restrict__ sb,
                          f16* __restrict__ dst, int K, int logK, int total) {
  int i = blockIdx.x * blockDim.x + threadIdx.x;
  if (i >= total) return;
  int k = i & (K - 1);
  int n = i >> logK;
  int d = n >> 10;
  int rem = n & 1023;
  int j = rem >> 2, g = rem & 3;
  const float* s = d ? sb : sf;
  dst[i] = (f16)s[(size_t)((g << 8) + j) * K + k];
}

__global__ void k_cvt_whh(const float* __restrict__ sf, const float* __restrict__ sb,
                          f16* __restrict__ dst) {
  int i = blockIdx.x * blockDim.x + threadIdx.x;
  if (i >= 524288) return;
  int d = i >> 18, rem = i & 262143;
  dst[i] = (f16)((d ? sb : sf)[rem]);
}

// ---------------- GEMM: C[m][n] = sum_k A[m][k]*B[n][k], C fp16 [M][2048] ----------------

template<int KD, bool GATHER>
__global__ __launch_bounds__(256)
void k_gemm(const f16* __restrict__ Abase, const f16* __restrict__ Bmat,
            const int* __restrict__ xtok, f16* __restrict__ C) {
  __shared__ __align__(16) char Al[128 * 64 * 2];
  __shared__ __align__(16) char Bl[128 * 64 * 2];
  __shared__ int toks[128];
  const int tid = threadIdx.x;
  const int lane = tid & 63, wave = tid >> 6;
  const int mt = blockIdx.x & 255;
  const int nt = blockIdx.x >> 8;
  const int Mb = mt * 128, Nb = nt * 128;

  if (GATHER) {
    if (tid < 128) {
      int m = Mb + tid;
      toks[tid] = xtok[(m & 63) * 512 + (m >> 6)];
    }
  }
  __syncthreads();

  const f16* asrc[4]; const f16* bsrc[4];
#pragma unroll
  for (int it = 0; it < 4; ++it) {
    int g = it * 256 + tid;
    int row = g >> 3, gc = g & 7;
    if (GATHER) asrc[it] = Abase + (size_t)toks[row] * KD + gc * 8;
    else        asrc[it] = Abase + (size_t)(Mb + row) * KD + gc * 8;
    bsrc[it] = Bmat + (size_t)(Nb + row) * KD + gc * 8;
  }

  floatx4 acc[4][4];
#pragma unroll
  for (int mi = 0; mi < 4; ++mi)
#pragma unroll
    for (int ni = 0; ni < 4; ++ni)
      acc[mi][ni] = (floatx4){0.f, 0.f, 0.f, 0.f};

  const int wr = wave >> 1, wc = wave & 1;

  for (int kt = 0; kt < KD / 64; ++kt) {
    __syncthreads();
#ifdef HAS_GLL
#pragma unroll
    for (int it = 0; it < 4; ++it) {
      __builtin_amdgcn_global_load_lds(
          (const __attribute__((address_space(1))) void*)(asrc[it]),
          (__attribute__((address_space(3))) void*)(Al + (it * 256 + wave * 64) * 16), 16, 0, 0);
      __builtin_amdgcn_global_load_lds(
          (const __attribute__((address_space(1))) void*)(bsrc[it]),
          (__attribute__((address_space(3))) void*)(Bl + (it * 256 + wave * 64) * 16), 16, 0, 0);
      asrc[it] += 64; bsrc[it] += 64;
    }
#else
    uint4 va[4], vb[4];
#pragma unroll
    for (int it = 0; it < 4; ++it) {
      va[it] = *(const uint4*)(asrc[it]);
      vb[it] = *(const uint4*)(bsrc[it]);
      asrc[it] += 64; bsrc[it] += 64;
    }
#pragma unroll
    for (int it = 0; it < 4; ++it) {
      *(uint4*)(Al + (it * 256 + wave * 64) * 16 + lane * 16) = va[it];
      *(uint4*)(Bl + (it * 256 + wave * 64) * 16 + lane * 16) = vb[it];
    }
#endif
    __syncthreads();

#pragma unroll
    for (int kk = 0; kk < 2; ++kk) {
      half8 av[4], bv[4];
#pragma unroll
      for (int mi = 0; mi < 4; ++mi) {
        int row = wr * 64 + mi * 16 + (lane & 15);
        av[mi] = *(const half8*)(Al + row * 128 + kk * 64 + (lane >> 4) * 16);
      }
#pragma unroll
      for (int ni = 0; ni < 4; ++ni) {
        int row = wc * 64 + ni * 16 + (lane & 15);
        bv[ni] = *(const half8*)(Bl + row * 128 + kk * 64 + (lane >> 4) * 16);
      }
#pragma unroll
      for (int mi = 0; mi < 4; ++mi)
#pragma unroll
        for (int ni = 0; ni < 4; ++ni)
          acc[mi][ni] = __builtin_amdgcn_mfma_f32_16x16x32_f16(av[mi], bv[ni], acc[mi][ni], 0, 0, 0);
    }
  }

#pragma unroll
  for (int mi = 0; mi < 4; ++mi) {
#pragma unroll
    for (int ni = 0; ni < 4; ++ni) {
      floatx4 v = acc[mi][ni];
      int n = Nb + wc * 64 + ni * 16 + (lane & 15);
#pragma unroll
      for (int r = 0; r < 4; ++r) {
        int m = Mb + wr * 64 + mi * 16 + (lane >> 4) * 4 + r;
        C[(size_t)m * 2048 + n] = (f16)v[r];
      }
    }
  }
}

// ---------------- scan body (OWNBASE compile-time; 4 slices interleaved) ----------------

template<int LAYER, int OWNBASE>
__device__ __forceinline__ void scan_body(
    const f16* __restrict__ proj, const f16* __restrict__ whh,
    const float* __restrict__ bias_f, const float* __restrict__ bias_b,
    f16* ring, float* __restrict__ finalh, unsigned* __restrict__ ctr,
    char* Hl) {
  constexpr int PEERBASE = 128 - OWNBASE;
  constexpr int JH = OWNBASE >> 7;
  const int tid = threadIdx.x, lane = tid & 63, wave = tid >> 6;
  const int d = blockIdx.x & 1;
  const int rowsel = lane >> 4, l15 = lane & 15;
  const int jlocal = OWNBASE + wave * 16 + l15;   // output col within d-half (0..255)
  const int klocal = wave * 16 + l15;             // col within own 128-slice
  const int bA = l15;                              // A-fragment batch row

  // Whh fragment (shared by all 4 slices): wreg[g][kk], static idx only
  half8 wreg[4][8];
#pragma unroll
  for (int g = 0; g < 4; ++g)
#pragma unroll
    for (int kk = 0; kk < 8; ++kk)
      wreg[g][kk] = *(const half8*)(whh + ((size_t)(d * 1024 + g * 256 + jlocal)) * 256
                                    + kk * 32 + rowsel * 8);

  const float* bptr = d ? bias_b : bias_f;
  float bias[4];
#pragma unroll
  for (int g = 0; g < 4; ++g) bias[g] = bptr[g * 256 + jlocal];

  // zero LDS (4 slices x 2 parities x 16 x 128 f16 = 32 KB)
#pragma unroll
  for (int i = 0; i < 4; ++i)
    ((uint4*)Hl)[i * 512 + tid] = make_uint4(0, 0, 0, 0);
  // zero own j-half of guard slot, ALL 64 batch rows (h(-1)=0 for all slices)
  {
    const int gslot = d ? 513 : 0;
    int zr = tid >> 3, zc = (tid & 7) * 8;
    *(uint4*)(ring + ((size_t)gslot * 64 + zr) * 512 + d * 256 + OWNBASE + zc) =
        make_uint4(0, 0, 0, 0);
  }
  __syncthreads();
  if (tid == 0) {
#pragma unroll
    for (int sl = 0; sl < 4; ++sl)
      __hip_atomic_store(ctr + (d * 4 + sl) * 64 + JH * 16, 1u,
                         __ATOMIC_RELEASE, __HIP_MEMORY_SCOPE_AGENT);
  }

  float cst[4][4] = {};

  // prologue: proj rows for step 0, all slices
  uint2 pj[4][4];
  {
    int t0 = d ? 511 : 0;
#pragma unroll
    for (int sl = 0; sl < 4; ++sl)
#pragma unroll
      for (int r = 0; r < 4; ++r)
        pj[sl][r] = *(const uint2*)(proj + ((size_t)t0 * 64 + sl * 16 + rowsel * 4 + r) * 2048
                                    + d * 1024 + (size_t)jlocal * 4);
  }

  for (int s = 0; s < 512; ++s) {
    const int rslot = d ? 513 - s : s;
    const int wslot = d ? 512 - s : s + 1;
    const int sn = (s < 511) ? s + 1 : 511;
    const int tn = d ? 511 - sn : sn;

#pragma unroll
    for (int sl = 0; sl < 4; ++sl) {
      unsigned* flagOwn  = ctr + (d * 4 + sl) * 64 + JH * 16;
      unsigned* flagPeer = ctr + (d * 4 + sl) * 64 + (1 - JH) * 16;
      const int bbase = sl * 16;

      // 1) consume: tid0 relaxed poll (>= s+1) + ONE acquire, barrier broadcast
      if (tid == 0) {
        unsigned target = (unsigned)(s + 1);
        unsigned v; int gd = 0;
        do {
          v = __hip_atomic_load(flagPeer, __ATOMIC_RELAXED, __HIP_MEMORY_SCOPE_AGENT);
        } while (v < target && ++gd < (1 << 18));
        (void)__hip_atomic_load(flagPeer, __ATOMIC_ACQUIRE, __HIP_MEMORY_SCOPE_AGENT);
      }
      __syncthreads();

      // 2) peer-half loads + next-step proj prefetch (latency under own-half MFMA)
      uint4 a4p[4];
      {
        const f16* pr = ring + ((size_t)rslot * 64 + bbase + bA) * 512 + d * 256 + PEERBASE
                        + rowsel * 8;
#pragma unroll
        for (int i = 0; i < 4; ++i)
          a4p[i] = *(const uint4*)(pr + i * 32);
      }
      uint2 pjn[4];
#pragma unroll
      for (int r = 0; r < 4; ++r)
        pjn[r] = *(const uint2*)(proj + ((size_t)tn * 64 + bbase + rowsel * 4 + r) * 2048
                                 + d * 1024 + (size_t)jlocal * 4);

      // 3) acc = proj + bias
      floatx4 acc[4];
#pragma unroll
      for (int r = 0; r < 4; ++r) {
        union { uint2 u; f16 h[4]; } cv; cv.u = pj[sl][r];
        acc[0][r] = (float)cv.h[0] + bias[0];
        acc[1][r] = (float)cv.h[1] + bias[1];
        acc[2][r] = (float)cv.h[2] + bias[2];
        acc[3][r] = (float)cv.h[3] + bias[3];
      }

      // 4) own-half MFMA from LDS (parity (s&1)^1), swizzled; static wreg idx
      {
        const char* rb = Hl + sl * 8192 + ((s & 1) ^ 1) * 4096;
        const int swz = (bA & 7) << 4;
#pragma unroll
        for (int i = 0; i < 4; ++i) {
          uint4 a4o = *(const uint4*)(rb + ((bA * 256 + i * 64 + rowsel * 16) ^ swz));
          half8 av = __builtin_bit_cast(half8, a4o);
#pragma unroll
          for (int g = 0; g < 4; ++g)
            acc[g] = __builtin_amdgcn_mfma_f32_16x16x32_f16(av, wreg[g][(OWNBASE >> 5) + i],
                                                            acc[g], 0, 0, 0);
        }
      }

      // 5) peer-half MFMA
#pragma unroll
      for (int i = 0; i < 4; ++i) {
        half8 av = __builtin_bit_cast(half8, a4p[i]);
#pragma unroll
        for (int g = 0; g < 4; ++g)
          acc[g] = __builtin_amdgcn_mfma_f32_16x16x32_f16(av, wreg[g][(PEERBASE >> 5) + i],
                                                          acc[g], 0, 0, 0);
      }

      // 6) gates -> h, c
      float hvv[4];
      f16 hhv[4];
#pragma unroll
      for (int r = 0; r < 4; ++r) {
        float iv = sigf(acc[0][r]);
        float fv = sigf(acc[1][r]);
        float gv = tanhf_(acc[2][r]);
        float ov = sigf(acc[3][r]);
        cst[sl][r] = fv * cst[sl][r] + iv * gv;
        hvv[r] = ov * tanhf_(cst[sl][r]);
        hhv[r] = (f16)hvv[r];
      }

      // 7) stores: LDS own-half (parity s&1, swizzled) + ring own chunk
      {
        char* wbuf = Hl + sl * 8192 + (s & 1) * 4096;
#pragma unroll
        for (int r = 0; r < 4; ++r) {
          int row = rowsel * 4 + r;
          *(f16*)(wbuf + ((row * 256 + klocal * 2) ^ ((row & 7) << 4))) = hhv[r];
          ring[((size_t)wslot * 64 + bbase + row) * 512 + d * 256 + jlocal] = hhv[r];
        }
      }
      if (LAYER == 1 && s == 511) {
#pragma unroll
        for (int r = 0; r < 4; ++r)
          finalh[(size_t)(d * 64 + bbase + rowsel * 4 + r) * 256 + jlocal] = hvv[r];
      }

      // 8) barrier (drains all waves' stores), then tid0 publishes this slice
      __syncthreads();
      if (tid == 0)
        __hip_atomic_store(flagOwn, (unsigned)(s + 2), __ATOMIC_RELEASE,
                           __HIP_MEMORY_SCOPE_AGENT);

#pragma unroll
      for (int r = 0; r < 4; ++r) pj[sl][r] = pjn[r];
    }
  }
}

template<int LAYER>
__global__ __launch_bounds__(512, 2)
void k_scan(const f16* __restrict__ proj, const f16* __restrict__ whh,
            const float* __restrict__ bias_f, const float* __restrict__ bias_b,
            f16* ring, float* __restrict__ finalh, unsigned* __restrict__ ctr) {
  __shared__ __align__(16) char Hl[32768];  // 4 slices x 2 parity x [16][128] f16
  if ((blockIdx.x >> 1) == 0)
    scan_body<LAYER, 0>(proj, whh, bias_f, bias_b, ring, finalh, ctr, Hl);
  else
    scan_body<LAYER, 128>(proj, whh, bias_f, bias_b, ring, finalh, ctr, Hl);
}

// ---------------- final linear ----------------
__global__ void k_final(const float* __restrict__ fh, const float* __restrict__ wlin,
                        const float* __restrict__ blin, float* __restrict__ out) {
  int tid = threadIdx.x;
  int b = tid >> 2, part = tid & 3;
  float sum = 0.f;
#pragma unroll 4
  for (int jj = 0; jj < 128; ++jj) {
    int j = part * 128 + jj;
    float lastv = (j < 256) ? fh[b * 256 + j] : fh[(64 + b) * 256 + (j - 256)];
    sum += lastv * wlin[j];
  }
  sum += __shfl_xor(sum, 1);
  sum += __shfl_xor(sum, 2);
  if (part == 0) out[b] = sum + blin[0];
}

// ---------------- host ----------------
extern "C" void kernel_launch(void* const* d_in, const int* in_sizes, int n_in,
                              void* d_out, int out_size, void* d_ws, size_t ws_size,
                              hipStream_t stream) {
  const int*   x     = (const int*)  d_in[0];
  const float* embed = (const float*)d_in[1];
  const float* wih0f = (const float*)d_in[2];
  const float* whh0f = (const float*)d_in[3];
  const float* b0f   = (const float*)d_in[4];
  const float* wih0b = (const float*)d_in[5];
  const float* whh0b = (const float*)d_in[6];
  const float* b0b   = (const float*)d_in[7];
  const float* wih1f = (const float*)d_in[8];
  const float* whh1f = (const float*)d_in[9];
  const float* b1f   = (const float*)d_in[10];
  const float* wih1b = (const float*)d_in[11];
  const float* whh1b = (const float*)d_in[12];
  const float* b1b   = (const float*)d_in[13];
  const float* wlin  = (const float*)d_in[14];
  const float* blin  = (const float*)d_in[15];

  char* ws = (char*)d_ws;
  size_t off = 0;
  auto alloc = [&](size_t bytes) {
    char* p = ws + off;
    off = (off + bytes + 511) & ~(size_t)511;
    return p;
  };
  f16* embed16 = (f16*)alloc((size_t)50000 * 256 * 2);
  f16* wih0_16 = (f16*)alloc((size_t)2048 * 256 * 2);
  f16* wih1_16 = (f16*)alloc((size_t)2048 * 512 * 2);
  f16* whh0_16 = (f16*)alloc((size_t)2 * 1024 * 256 * 2);
  f16* whh1_16 = (f16*)alloc((size_t)2 * 1024 * 256 * 2);
  f16* proj    = (f16*)alloc((size_t)32768 * 2048 * 2);
  f16* ring    = (f16*)alloc((size_t)514 * 64 * 512 * 2);  // exchange ring; slots 1..512 = h0
  float* fh    = (float*)alloc((size_t)2 * 64 * 256 * 4);
  unsigned* ctr = (unsigned*)alloc((size_t)8 * 64 * 4);

  if (off > ws_size) {
    hipMemsetAsync(d_out, 0, (size_t)out_size * 4, stream);
    return;
  }

  k_cvt_embed<<<(12800000 / 8 + 255) / 256, 256, 0, stream>>>(embed, embed16, 12800000 / 8);
  k_cvt_wih<<<(2048 * 256 + 255) / 256, 256, 0, stream>>>(wih0f, wih0b, wih0_16, 256, 8, 2048 * 256);
  k_cvt_wih<<<(2048 * 512 + 255) / 256, 256, 0, stream>>>(wih1f, wih1b, wih1_16, 512, 9, 2048 * 512);
  k_cvt_whh<<<(524288 + 255) / 256, 256, 0, stream>>>(whh0f, whh0b, whh0_16);
  k_cvt_whh<<<(524288 + 255) / 256, 256, 0, stream>>>(whh1f, whh1b, whh1_16);

  // layer 0 input projection: [32768,256] x [2048,256]^T -> proj
  k_gemm<256, true><<<4096, 256, 0, stream>>>(embed16, wih0_16, x, proj);
  hipMemsetAsync(ctr, 0, (size_t)8 * 64 * 4, stream);
  k_scan<0><<<4, 512, 0, stream>>>(proj, whh0_16, b0f, b0b, ring, nullptr, ctr);

  // layer 1 input projection: A = ring slots 1..512 ([32768,512]), B = wih1
  k_gemm<512, false><<<4096, 256, 0, stream>>>(ring + 32768, wih1_16, nullptr, proj);
  hipMemsetAsync(ctr, 0, (size_t)8 * 64 * 4, stream);
  k_scan<1><<<4, 512, 0, stream>>>(proj, whh1_16, b1f, b1b, ring, fh, ctr);

  k_final<<<1, 256, 0, stream>>>(fh, wlin, blin, (float*)d_out);
}

// Round 11
// 7054.342 us; speedup vs baseline: 1.6517x; 1.6517x over previous
//
#include <hip/hip_runtime.h>
#include <hip/hip_fp16.h>

// ReviewAnalyzeModel: 2-layer biLSTM, B=64 T=512 E=256 H=256, V=50000.
// prep(cvt fp16) -> GEMM proj0 -> scan0 -> GEMM proj1 -> scan1 -> final linear.
// Scan R11: 16 blocks x 512 thr; group gid=blockIdx&7 = (dir, batch-slice of 16);
// blk owns 128 of 256 hidden cols (compile-time OWNBASE; weights in regs).
// LOCK-FREE MALL protocol (zero cache-maintenance ops):
//   - h exchange: relaxed agent atomic ushort stores -> MALL; relaxed agent
//     atomic ull loads <- MALL (atomic loads proven cache-bypassing: R3/R9 spins).
//   - publish: s_waitcnt vmcnt(0) (data acked at MALL) then relaxed agent
//     fetch_add on the wave's own flag (RMW executes at coherence point).
//   - consume: wave polls all 16 group flags with relaxed atomic loads + __all.
//   No release/acquire (no wbl2/inv), no __syncthreads, no LDS. Ring slots are
//   monotonic per step (slot t+1; guards 0/513) so no buffer-reuse hazards.

typedef _Float16 f16;
typedef _Float16 half8 __attribute__((ext_vector_type(8)));
typedef float floatx4 __attribute__((ext_vector_type(4)));
typedef unsigned long long u64;

#if __has_builtin(__builtin_amdgcn_global_load_lds)
#define HAS_GLL 1
#endif

#if __has_builtin(__builtin_amdgcn_exp2f)
#define EXP2F __builtin_amdgcn_exp2f
#else
#define EXP2F exp2f
#endif
#if __has_builtin(__builtin_amdgcn_rcpf)
#define RCPF __builtin_amdgcn_rcpf
#else
#define RCPF(x) (1.0f/(x))
#endif

__device__ __forceinline__ float sigf(float x) {
  return RCPF(1.f + EXP2F(-1.4426950408889634f * x));
}
__device__ __forceinline__ float tanhf_(float x) {
  return 2.f * RCPF(1.f + EXP2F(-2.8853900817779268f * x)) - 1.f;
}

// ---------------- prep kernels ----------------

__global__ void k_cvt_embed(const float* __restrict__ src, f16* __restrict__ dst, int n8) {
  int i = blockIdx.x * blockDim.x + threadIdx.x;
  if (i >= n8) return;
  const float4* s = (const float4*)(src + (size_t)i * 8);
  float4 a = s[0], b = s[1];
  half8 h = { (f16)a.x,(f16)a.y,(f16)a.z,(f16)a.w,(f16)b.x,(f16)b.y,(f16)b.z,(f16)b.w };
  *(half8*)(dst + (size_t)i * 8) = h;
}

// dst[n'][k], n' = d*1024 + j*4 + gate ; src row (gate*256+j) of Wih_l?_{f,b}
__global__ void k_cvt_wih(const float* __restrict__ sf, const float* __restrict__ sb,
                          f16* __restrict__ dst, int K, int logK, int total) {
  int i = blockIdx.x * blockDim.x + threadIdx.x;
  if (i >= total) return;
  int k = i & (K - 1);
  int n = i >> logK;
  int d = n >> 10;
  int rem = n & 1023;
  int j = rem >> 2, g = rem & 3;
  const float* s = d ? sb : sf;
  dst[i] = (f16)s[(size_t)((g << 8) + j) * K + k];
}

__global__ void k_cvt_whh(const float* __restrict__ sf, const float* __restrict__ sb,
                          f16* __restrict__ dst) {
  int i = blockIdx.x * blockDim.x + threadIdx.x;
  if (i >= 524288) return;
  int d = i >> 18, rem = i & 262143;
  dst[i] = (f16)((d ? sb : sf)[rem]);
}

// ---------------- GEMM: C[m][n] = sum_k A[m][k]*B[n][k], C fp16 [M][2048] ----------------

template<int KD, bool GATHER>
__global__ __launch_bounds__(256)
void k_gemm(const f16* __restrict__ Abase, const f16* __restrict__ Bmat,
            const int* __restrict__ xtok, f16* __restrict__ C) {
  __shared__ __align__(16) char Al[128 * 64 * 2];
  __shared__ __align__(16) char Bl[128 * 64 * 2];
  __shared__ int toks[128];
  const int tid = threadIdx.x;
  const int lane = tid & 63, wave = tid >> 6;
  const int mt = blockIdx.x & 255;
  const int nt = blockIdx.x >> 8;
  const int Mb = mt * 128, Nb = nt * 128;

  if (GATHER) {
    if (tid < 128) {
      int m = Mb + tid;
      toks[tid] = xtok[(m & 63) * 512 + (m >> 6)];
    }
  }
  __syncthreads();

  const f16* asrc[4]; const f16* bsrc[4];
#pragma unroll
  for (int it = 0; it < 4; ++it) {
    int g = it * 256 + tid;
    int row = g >> 3, gc = g & 7;
    if (GATHER) asrc[it] = Abase + (size_t)toks[row] * KD + gc * 8;
    else        asrc[it] = Abase + (size_t)(Mb + row) * KD + gc * 8;
    bsrc[it] = Bmat + (size_t)(Nb + row) * KD + gc * 8;
  }

  floatx4 acc[4][4];
#pragma unroll
  for (int mi = 0; mi < 4; ++mi)
#pragma unroll
    for (int ni = 0; ni < 4; ++ni)
      acc[mi][ni] = (floatx4){0.f, 0.f, 0.f, 0.f};

  const int wr = wave >> 1, wc = wave & 1;

  for (int kt = 0; kt < KD / 64; ++kt) {
    __syncthreads();
#ifdef HAS_GLL
#pragma unroll
    for (int it = 0; it < 4; ++it) {
      __builtin_amdgcn_global_load_lds(
          (const __attribute__((address_space(1))) void*)(asrc[it]),
          (__attribute__((address_space(3))) void*)(Al + (it * 256 + wave * 64) * 16), 16, 0, 0);
      __builtin_amdgcn_global_load_lds(
          (const __attribute__((address_space(1))) void*)(bsrc[it]),
          (__attribute__((address_space(3))) void*)(Bl + (it * 256 + wave * 64) * 16), 16, 0, 0);
      asrc[it] += 64; bsrc[it] += 64;
    }
#else
    uint4 va[4], vb[4];
#pragma unroll
    for (int it = 0; it < 4; ++it) {
      va[it] = *(const uint4*)(asrc[it]);
      vb[it] = *(const uint4*)(bsrc[it]);
      asrc[it] += 64; bsrc[it] += 64;
    }
#pragma unroll
    for (int it = 0; it < 4; ++it) {
      *(uint4*)(Al + (it * 256 + wave * 64) * 16 + lane * 16) = va[it];
      *(uint4*)(Bl + (it * 256 + wave * 64) * 16 + lane * 16) = vb[it];
    }
#endif
    __syncthreads();

#pragma unroll
    for (int kk = 0; kk < 2; ++kk) {
      half8 av[4], bv[4];
#pragma unroll
      for (int mi = 0; mi < 4; ++mi) {
        int row = wr * 64 + mi * 16 + (lane & 15);
        av[mi] = *(const half8*)(Al + row * 128 + kk * 64 + (lane >> 4) * 16);
      }
#pragma unroll
      for (int ni = 0; ni < 4; ++ni) {
        int row = wc * 64 + ni * 16 + (lane & 15);
        bv[ni] = *(const half8*)(Bl + row * 128 + kk * 64 + (lane >> 4) * 16);
      }
#pragma unroll
      for (int mi = 0; mi < 4; ++mi)
#pragma unroll
        for (int ni = 0; ni < 4; ++ni)
          acc[mi][ni] = __builtin_amdgcn_mfma_f32_16x16x32_f16(av[mi], bv[ni], acc[mi][ni], 0, 0, 0);
    }
  }

#pragma unroll
  for (int mi = 0; mi < 4; ++mi) {
#pragma unroll
    for (int ni = 0; ni < 4; ++ni) {
      floatx4 v = acc[mi][ni];
      int n = Nb + wc * 64 + ni * 16 + (lane & 15);
#pragma unroll
      for (int r = 0; r < 4; ++r) {
        int m = Mb + wr * 64 + mi * 16 + (lane >> 4) * 4 + r;
        C[(size_t)m * 2048 + n] = (f16)v[r];
      }
    }
  }
}

// ---------------- scan body (R11: lock-free MALL protocol, per-wave autonomy) ----------------

template<int LAYER, int OWNBASE>
__device__ __forceinline__ void scan_body(
    const f16* __restrict__ proj, const f16* __restrict__ whh,
    const float* __restrict__ bias_f, const float* __restrict__ bias_b,
    f16* ring, float* __restrict__ finalh, unsigned* ctr) {
  constexpr int JH = OWNBASE >> 7;
  const int tid = threadIdx.x, lane = tid & 63, wave = tid >> 6;
  const int gid = blockIdx.x & 7;
  const int d = gid & 1;
  const int bbase = (gid >> 1) * 16;
  const int rowsel = lane >> 4, l15 = lane & 15;
  const int jlocal = OWNBASE + wave * 16 + l15;   // output col within d-half (0..255)
  const int bA = l15;                              // A-fragment batch row
  unsigned* flags = ctr + gid * 64;                // 16 per-wave flags per group
  const int fidx = JH * 8 + wave;

  // Whh fragment: wreg[g][kk] (static idx only; plain cached loads)
  half8 wreg[4][8];
#pragma unroll
  for (int g = 0; g < 4; ++g)
#pragma unroll
    for (int kk = 0; kk < 8; ++kk)
      wreg[g][kk] = *(const half8*)(whh + ((size_t)(d * 1024 + g * 256 + jlocal)) * 256
                                    + kk * 32 + rowsel * 8);

  const float* bptr = d ? bias_b : bias_f;
  float bias[4];
#pragma unroll
  for (int g = 0; g < 4; ++g) bias[g] = bptr[g * 256 + jlocal];

  // zero own 128-col chunk of guard slot via MALL atomics (16 rows x 128 cols).
  // tid>>5 = row 0..15 (wave-aligned: wave w covers rows 2w,2w+1), (tid&31)*4 cols.
  {
    const int gslot = d ? 513 : 0;
    u64* zp = (u64*)(ring + ((size_t)gslot * 64 + bbase + (tid >> 5)) * 512
                     + d * 256 + OWNBASE + (tid & 31) * 4);
    __hip_atomic_store(zp, 0ull, __ATOMIC_RELAXED, __HIP_MEMORY_SCOPE_AGENT);
  }
  asm volatile("s_waitcnt vmcnt(0)" ::: "memory");
  if (lane == 0)
    __hip_atomic_fetch_add(&flags[fidx], 1u, __ATOMIC_RELAXED, __HIP_MEMORY_SCOPE_AGENT);

  float cst[4] = {0.f, 0.f, 0.f, 0.f};

  // prologue: proj row for step 0 (plain cached loads; proj is read-only here)
  uint2 pj[4];
  {
    int t0 = d ? 511 : 0;
#pragma unroll
    for (int r = 0; r < 4; ++r)
      pj[r] = *(const uint2*)(proj + ((size_t)t0 * 64 + bbase + rowsel * 4 + r) * 2048
                              + d * 1024 + (size_t)jlocal * 4);
  }

  for (int s = 0; s < 512; ++s) {
    // 1) poll: all 16 waves of the group published step s-1 (flag >= s+1).
    //    Relaxed agent atomic loads read the coherence point (proven R3/R9).
    {
      unsigned target = (unsigned)(s + 1);
      int gd = 0;
      bool ok;
      do {
        unsigned v = __hip_atomic_load(&flags[lane & 15], __ATOMIC_RELAXED,
                                       __HIP_MEMORY_SCOPE_AGENT);
        ok = (bool)__all((int)(v >= target));
      } while (!ok && ++gd < (1 << 18));
    }

    // 2) A-fragments: full 256-k row via 16 x 8B relaxed atomic loads (MALL)
    const int rslot = d ? 513 - s : s;
    u64* hrow = (u64*)(ring + ((size_t)rslot * 64 + bbase + bA) * 512
                       + d * 256 + rowsel * 8);
    u64 a8[16];
#pragma unroll
    for (int kk = 0; kk < 8; ++kk) {
      a8[2 * kk]     = __hip_atomic_load(hrow + kk * 8,     __ATOMIC_RELAXED,
                                         __HIP_MEMORY_SCOPE_AGENT);
      a8[2 * kk + 1] = __hip_atomic_load(hrow + kk * 8 + 1, __ATOMIC_RELAXED,
                                         __HIP_MEMORY_SCOPE_AGENT);
    }

    // 3) acc = proj + bias
    floatx4 acc[4];
#pragma unroll
    for (int r = 0; r < 4; ++r) {
      union { uint2 u; f16 h[4]; } cv; cv.u = pj[r];
      acc[0][r] = (float)cv.h[0] + bias[0];
      acc[1][r] = (float)cv.h[1] + bias[1];
      acc[2][r] = (float)cv.h[2] + bias[2];
      acc[3][r] = (float)cv.h[3] + bias[3];
    }

    // 4) 32 MFMAs over k=0..255
#pragma unroll
    for (int kk = 0; kk < 8; ++kk) {
      union { struct { u64 lo, hi; } w; half8 h; } fr;
      fr.w.lo = a8[2 * kk]; fr.w.hi = a8[2 * kk + 1];
      half8 av = fr.h;
#pragma unroll
      for (int g = 0; g < 4; ++g)
        acc[g] = __builtin_amdgcn_mfma_f32_16x16x32_f16(av, wreg[g][kk], acc[g], 0, 0, 0);
    }

    // 5) gates -> h,c; own h cols to ring slot via relaxed atomic ushort stores
    const int wslot = d ? 512 - s : s + 1;
    float hvv[4];
#pragma unroll
    for (int r = 0; r < 4; ++r) {
      float iv = sigf(acc[0][r]);
      float fv = sigf(acc[1][r]);
      float gv = tanhf_(acc[2][r]);
      float ov = sigf(acc[3][r]);
      cst[r] = fv * cst[r] + iv * gv;
      hvv[r] = ov * tanhf_(cst[r]);
      f16 hh = (f16)hvv[r];
      unsigned short hu = __builtin_bit_cast(unsigned short, hh);
      __hip_atomic_store(
          (unsigned short*)(ring + ((size_t)wslot * 64 + bbase + rowsel * 4 + r) * 512
                            + d * 256 + jlocal),
          hu, __ATOMIC_RELAXED, __HIP_MEMORY_SCOPE_AGENT);
    }
    if (LAYER == 1 && s == 511) {
#pragma unroll
      for (int r = 0; r < 4; ++r)
        finalh[(size_t)(d * 64 + bbase + rowsel * 4 + r) * 256 + jlocal] = hvv[r];
    }

    // 6) publish: wait data acks (completion order), then remote RMW on own flag
    asm volatile("s_waitcnt vmcnt(0)" ::: "memory");
    if (lane == 0)
      __hip_atomic_fetch_add(&flags[fidx], 1u, __ATOMIC_RELAXED, __HIP_MEMORY_SCOPE_AGENT);

    // 7) prefetch next step's proj AFTER publish (off the vmcnt critical path;
    //    consumed next iteration, hidden under the poll + A-loads)
    {
      int sn = (s < 511) ? s + 1 : 511;
      int tn = d ? 511 - sn : sn;
#pragma unroll
      for (int r = 0; r < 4; ++r)
        pj[r] = *(const uint2*)(proj + ((size_t)tn * 64 + bbase + rowsel * 4 + r) * 2048
                                + d * 1024 + (size_t)jlocal * 4);
    }
  }
}

template<int LAYER>
__global__ __launch_bounds__(512, 1)
void k_scan(const f16* __restrict__ proj, const f16* __restrict__ whh,
            const float* __restrict__ bias_f, const float* __restrict__ bias_b,
            f16* ring, float* __restrict__ finalh, unsigned* ctr) {
  if ((blockIdx.x >> 3) == 0)
    scan_body<LAYER, 0>(proj, whh, bias_f, bias_b, ring, finalh, ctr);
  else
    scan_body<LAYER, 128>(proj, whh, bias_f, bias_b, ring, finalh, ctr);
}

// ---------------- final linear ----------------
__global__ void k_final(const float* __restrict__ fh, const float* __restrict__ wlin,
                        const float* __restrict__ blin, float* __restrict__ out) {
  int tid = threadIdx.x;
  int b = tid >> 2, part = tid & 3;
  float sum = 0.f;
#pragma unroll 4
  for (int jj = 0; jj < 128; ++jj) {
    int j = part * 128 + jj;
    float lastv = (j < 256) ? fh[b * 256 + j] : fh[(64 + b) * 256 + (j - 256)];
    sum += lastv * wlin[j];
  }
  sum += __shfl_xor(sum, 1);
  sum += __shfl_xor(sum, 2);
  if (part == 0) out[b] = sum + blin[0];
}

// ---------------- host ----------------
extern "C" void kernel_launch(void* const* d_in, const int* in_sizes, int n_in,
                              void* d_out, int out_size, void* d_ws, size_t ws_size,
                              hipStream_t stream) {
  const int*   x     = (const int*)  d_in[0];
  const float* embed = (const float*)d_in[1];
  const float* wih0f = (const float*)d_in[2];
  const float* whh0f = (const float*)d_in[3];
  const float* b0f   = (const float*)d_in[4];
  const float* wih0b = (const float*)d_in[5];
  const float* whh0b = (const float*)d_in[6];
  const float* b0b   = (const float*)d_in[7];
  const float* wih1f = (const float*)d_in[8];
  const float* whh1f = (const float*)d_in[9];
  const float* b1f   = (const float*)d_in[10];
  const float* wih1b = (const float*)d_in[11];
  const float* whh1b = (const float*)d_in[12];
  const float* b1b   = (const float*)d_in[13];
  const float* wlin  = (const float*)d_in[14];
  const float* blin  = (const float*)d_in[15];

  char* ws = (char*)d_ws;
  size_t off = 0;
  auto alloc = [&](size_t bytes) {
    char* p = ws + off;
    off = (off + bytes + 511) & ~(size_t)511;
    return p;
  };
  f16* embed16 = (f16*)alloc((size_t)50000 * 256 * 2);
  f16* wih0_16 = (f16*)alloc((size_t)2048 * 256 * 2);
  f16* wih1_16 = (f16*)alloc((size_t)2048 * 512 * 2);
  f16* whh0_16 = (f16*)alloc((size_t)2 * 1024 * 256 * 2);
  f16* whh1_16 = (f16*)alloc((size_t)2 * 1024 * 256 * 2);
  f16* proj    = (f16*)alloc((size_t)32768 * 2048 * 2);
  f16* ring    = (f16*)alloc((size_t)514 * 64 * 512 * 2);  // exchange ring; slots 1..512 = h0
  float* fh    = (float*)alloc((size_t)2 * 64 * 256 * 4);
  unsigned* ctr = (unsigned*)alloc((size_t)8 * 64 * 4);

  if (off > ws_size) {
    hipMemsetAsync(d_out, 0, (size_t)out_size * 4, stream);
    return;
  }

  k_cvt_embed<<<(12800000 / 8 + 255) / 256, 256, 0, stream>>>(embed, embed16, 12800000 / 8);
  k_cvt_wih<<<(2048 * 256 + 255) / 256, 256, 0, stream>>>(wih0f, wih0b, wih0_16, 256, 8, 2048 * 256);
  k_cvt_wih<<<(2048 * 512 + 255) / 256, 256, 0, stream>>>(wih1f, wih1b, wih1_16, 512, 9, 2048 * 512);
  k_cvt_whh<<<(524288 + 255) / 256, 256, 0, stream>>>(whh0f, whh0b, whh0_16);
  k_cvt_whh<<<(524288 + 255) / 256, 256, 0, stream>>>(whh1f, whh1b, whh1_16);

  // layer 0 input projection: [32768,256] x [2048,256]^T -> proj
  k_gemm<256, true><<<4096, 256, 0, stream>>>(embed16, wih0_16, x, proj);
  hipMemsetAsync(ctr, 0, (size_t)8 * 64 * 4, stream);
  k_scan<0><<<16, 512, 0, stream>>>(proj, whh0_16, b0f, b0b, ring, nullptr, ctr);

  // layer 1 input projection: A = ring slots 1..512 ([32768,512]), B = wih1
  k_gemm<512, false><<<4096, 256, 0, stream>>>(ring + 32768, wih1_16, nullptr, proj);
  hipMemsetAsync(ctr, 0, (size_t)8 * 64 * 4, stream);
  k_scan<1><<<16, 512, 0, stream>>>(proj, whh1_16, b1f, b1b, ring, fh, ctr);

  k_final<<<1, 256, 0, stream>>>(fh, wlin, blin, (float*)d_out);
}

// Round 12
// 3299.717 us; speedup vs baseline: 3.5311x; 2.1379x over previous
//
#include <hip/hip_runtime.h>
#include <hip/hip_fp16.h>

// ReviewAnalyzeModel: 2-layer biLSTM, B=64 T=512 E=256 H=256, V=50000.
// prep(cvt fp16) -> GEMM proj0 -> scan0 -> GEMM proj1 -> scan1 -> final linear.
// Scan R12 = R9 skeleton + R11 fence-free MALL data path:
// 16 blocks x 512 thr (8 waves); group gid=blockIdx&7 = (dir, batch-slice of 16);
// blk owns 128 of 256 hidden cols (compile-time OWNBASE; weights in regs).
// Own j-half h via LDS (barrier). Peer half via ring (= h0, slot t+1, guards
// 0/513): producer writes own half with RELAXED AGENT ATOMIC ushort stores
// (write-through to MALL; R11-proven), barrier's vmcnt(0) drains them, tid0
// publishes with a RELAXED atomic store (no release/wbl2). Consumer: tid0
// RELAXED poll (no acquire/inv; R3/R9-proven observation) + barrier broadcast;
// peer half read with relaxed agent atomic u64 loads (MALL-fresh). Zero
// cache-maintenance ops per step.

typedef _Float16 f16;
typedef _Float16 half8 __attribute__((ext_vector_type(8)));
typedef float floatx4 __attribute__((ext_vector_type(4)));
typedef unsigned long long u64;

#if __has_builtin(__builtin_amdgcn_global_load_lds)
#define HAS_GLL 1
#endif

#if __has_builtin(__builtin_amdgcn_exp2f)
#define EXP2F __builtin_amdgcn_exp2f
#else
#define EXP2F exp2f
#endif
#if __has_builtin(__builtin_amdgcn_rcpf)
#define RCPF __builtin_amdgcn_rcpf
#else
#define RCPF(x) (1.0f/(x))
#endif

__device__ __forceinline__ float sigf(float x) {
  return RCPF(1.f + EXP2F(-1.4426950408889634f * x));
}
__device__ __forceinline__ float tanhf_(float x) {
  return 2.f * RCPF(1.f + EXP2F(-2.8853900817779268f * x)) - 1.f;
}

// ---------------- prep kernels ----------------

__global__ void k_cvt_embed(const float* __restrict__ src, f16* __restrict__ dst, int n8) {
  int i = blockIdx.x * blockDim.x + threadIdx.x;
  if (i >= n8) return;
  const float4* s = (const float4*)(src + (size_t)i * 8);
  float4 a = s[0], b = s[1];
  half8 h = { (f16)a.x,(f16)a.y,(f16)a.z,(f16)a.w,(f16)b.x,(f16)b.y,(f16)b.z,(f16)b.w };
  *(half8*)(dst + (size_t)i * 8) = h;
}

// dst[n'][k], n' = d*1024 + j*4 + gate ; src row (gate*256+j) of Wih_l?_{f,b}
__global__ void k_cvt_wih(const float* __restrict__ sf, const float* __restrict__ sb,
                          f16* __restrict__ dst, int K, int logK, int total) {
  int i = blockIdx.x * blockDim.x + threadIdx.x;
  if (i >= total) return;
  int k = i & (K - 1);
  int n = i >> logK;
  int d = n >> 10;
  int rem = n & 1023;
  int j = rem >> 2, g = rem & 3;
  const float* s = d ? sb : sf;
  dst[i] = (f16)s[(size_t)((g << 8) + j) * K + k];
}

__global__ void k_cvt_whh(const float* __restrict__ sf, const float* __restrict__ sb,
                          f16* __restrict__ dst) {
  int i = blockIdx.x * blockDim.x + threadIdx.x;
  if (i >= 524288) return;
  int d = i >> 18, rem = i & 262143;
  dst[i] = (f16)((d ? sb : sf)[rem]);
}

// ---------------- GEMM: C[m][n] = sum_k A[m][k]*B[n][k], C fp16 [M][2048] ----------------

template<int KD, bool GATHER>
__global__ __launch_bounds__(256)
void k_gemm(const f16* __restrict__ Abase, const f16* __restrict__ Bmat,
            const int* __restrict__ xtok, f16* __restrict__ C) {
  __shared__ __align__(16) char Al[128 * 64 * 2];
  __shared__ __align__(16) char Bl[128 * 64 * 2];
  __shared__ int toks[128];
  const int tid = threadIdx.x;
  const int lane = tid & 63, wave = tid >> 6;
  const int mt = blockIdx.x & 255;
  const int nt = blockIdx.x >> 8;
  const int Mb = mt * 128, Nb = nt * 128;

  if (GATHER) {
    if (tid < 128) {
      int m = Mb + tid;
      toks[tid] = xtok[(m & 63) * 512 + (m >> 6)];
    }
  }
  __syncthreads();

  const f16* asrc[4]; const f16* bsrc[4];
#pragma unroll
  for (int it = 0; it < 4; ++it) {
    int g = it * 256 + tid;
    int row = g >> 3, gc = g & 7;
    if (GATHER) asrc[it] = Abase + (size_t)toks[row] * KD + gc * 8;
    else        asrc[it] = Abase + (size_t)(Mb + row) * KD + gc * 8;
    bsrc[it] = Bmat + (size_t)(Nb + row) * KD + gc * 8;
  }

  floatx4 acc[4][4];
#pragma unroll
  for (int mi = 0; mi < 4; ++mi)
#pragma unroll
    for (int ni = 0; ni < 4; ++ni)
      acc[mi][ni] = (floatx4){0.f, 0.f, 0.f, 0.f};

  const int wr = wave >> 1, wc = wave & 1;

  for (int kt = 0; kt < KD / 64; ++kt) {
    __syncthreads();
#ifdef HAS_GLL
#pragma unroll
    for (int it = 0; it < 4; ++it) {
      __builtin_amdgcn_global_load_lds(
          (const __attribute__((address_space(1))) void*)(asrc[it]),
          (__attribute__((address_space(3))) void*)(Al + (it * 256 + wave * 64) * 16), 16, 0, 0);
      __builtin_amdgcn_global_load_lds(
          (const __attribute__((address_space(1))) void*)(bsrc[it]),
          (__attribute__((address_space(3))) void*)(Bl + (it * 256 + wave * 64) * 16), 16, 0, 0);
      asrc[it] += 64; bsrc[it] += 64;
    }
#else
    uint4 va[4], vb[4];
#pragma unroll
    for (int it = 0; it < 4; ++it) {
      va[it] = *(const uint4*)(asrc[it]);
      vb[it] = *(const uint4*)(bsrc[it]);
      asrc[it] += 64; bsrc[it] += 64;
    }
#pragma unroll
    for (int it = 0; it < 4; ++it) {
      *(uint4*)(Al + (it * 256 + wave * 64) * 16 + lane * 16) = va[it];
      *(uint4*)(Bl + (it * 256 + wave * 64) * 16 + lane * 16) = vb[it];
    }
#endif
    __syncthreads();

#pragma unroll
    for (int kk = 0; kk < 2; ++kk) {
      half8 av[4], bv[4];
#pragma unroll
      for (int mi = 0; mi < 4; ++mi) {
        int row = wr * 64 + mi * 16 + (lane & 15);
        av[mi] = *(const half8*)(Al + row * 128 + kk * 64 + (lane >> 4) * 16);
      }
#pragma unroll
      for (int ni = 0; ni < 4; ++ni) {
        int row = wc * 64 + ni * 16 + (lane & 15);
        bv[ni] = *(const half8*)(Bl + row * 128 + kk * 64 + (lane >> 4) * 16);
      }
#pragma unroll
      for (int mi = 0; mi < 4; ++mi)
#pragma unroll
        for (int ni = 0; ni < 4; ++ni)
          acc[mi][ni] = __builtin_amdgcn_mfma_f32_16x16x32_f16(av[mi], bv[ni], acc[mi][ni], 0, 0, 0);
    }
  }

#pragma unroll
  for (int mi = 0; mi < 4; ++mi) {
#pragma unroll
    for (int ni = 0; ni < 4; ++ni) {
      floatx4 v = acc[mi][ni];
      int n = Nb + wc * 64 + ni * 16 + (lane & 15);
#pragma unroll
      for (int r = 0; r < 4; ++r) {
        int m = Mb + wr * 64 + mi * 16 + (lane >> 4) * 4 + r;
        C[(size_t)m * 2048 + n] = (f16)v[r];
      }
    }
  }
}

// ---------------- scan body (OWNBASE compile-time; fence-free MALL protocol) ----------------

template<int LAYER, int OWNBASE>
__device__ __forceinline__ void scan_body(
    const f16* __restrict__ proj, const f16* __restrict__ whh,
    const float* __restrict__ bias_f, const float* __restrict__ bias_b,
    f16* ring, float* __restrict__ finalh, unsigned* ctr, char* Hl) {
  constexpr int PEERBASE = 128 - OWNBASE;
  constexpr int BLK = OWNBASE >> 7;
  const int tid = threadIdx.x, lane = tid & 63, wave = tid >> 6;
  const int gid = blockIdx.x & 7;
  const int d = gid & 1;
  const int bbase = (gid >> 1) * 16;
  const int rowsel = lane >> 4, l15 = lane & 15;
  const int jlocal = OWNBASE + wave * 16 + l15;   // output col within d-half (0..255)
  const int klocal = wave * 16 + l15;             // col within own 128-slice
  const int bA = l15;                              // A-fragment batch row
  unsigned* flagOwn  = ctr + gid * 64 + BLK * 16;
  unsigned* flagPeer = ctr + gid * 64 + (1 - BLK) * 16;

  // Whh fragment: wreg[g][kk] = B-fragment (gate g, absolute k-chunk kk) — static idx only
  half8 wreg[4][8];
#pragma unroll
  for (int g = 0; g < 4; ++g)
#pragma unroll
    for (int kk = 0; kk < 8; ++kk)
      wreg[g][kk] = *(const half8*)(whh + ((size_t)(d * 1024 + g * 256 + jlocal)) * 256
                                    + kk * 32 + rowsel * 8);

  const float* bptr = d ? bias_b : bias_f;
  float bias[4];
#pragma unroll
  for (int g = 0; g < 4; ++g) bias[g] = bptr[g * 256 + jlocal];

  // prologue zeros: LDS (both parity buffers) + own 128-col chunk of ring guard
  // slot via relaxed agent atomic u64 stores (write-through to MALL, R11-proven).
  *(uint4*)(Hl + tid * 16) = make_uint4(0, 0, 0, 0);
  {
    const int gslot = d ? 513 : 0;
    u64* zp = (u64*)(ring + ((size_t)gslot * 64 + bbase + (tid >> 5)) * 512
                     + d * 256 + OWNBASE + (tid & 31) * 4);
    __hip_atomic_store(zp, 0ull, __ATOMIC_RELAXED, __HIP_MEMORY_SCOPE_AGENT);
  }
  __syncthreads();  // pre-barrier vmcnt(0) drains all waves' atomic stores to MALL
  if (tid == 0)
    __hip_atomic_store(flagOwn, 1u, __ATOMIC_RELAXED, __HIP_MEMORY_SCOPE_AGENT);

  float cst[4] = {0.f, 0.f, 0.f, 0.f};

  // prologue: proj row for step 0
  uint2 pj[4];
  {
    int t0 = d ? 511 : 0;
#pragma unroll
    for (int r = 0; r < 4; ++r)
      pj[r] = *(const uint2*)(proj + ((size_t)t0 * 64 + bbase + rowsel * 4 + r) * 2048
                              + d * 1024 + (size_t)jlocal * 4);
  }

  for (int s = 0; s < 512; ++s) {
    // 1) consume: tid0 RELAXED poll of peer flag (>= s+1); barrier broadcast.
    //    No acquire: peer data is read via cache-bypassing atomic loads below.
    if (tid == 0) {
      unsigned target = (unsigned)(s + 1);
      unsigned v; int gd = 0;
      do {
        v = __hip_atomic_load(flagPeer, __ATOMIC_RELAXED, __HIP_MEMORY_SCOPE_AGENT);
      } while (v < target && ++gd < (1 << 18));
    }
    __syncthreads();

    // 2) peer-half A-fragments via relaxed agent atomic u64 loads (MALL-fresh);
    //    latency hidden under own-half LDS MFMA below.
    const int rslot = d ? 513 - s : s;
    u64 a8[8];
    {
      const u64* pr = (const u64*)(ring + ((size_t)rslot * 64 + bbase + bA) * 512
                                   + d * 256 + PEERBASE + rowsel * 8);
#pragma unroll
      for (int i = 0; i < 4; ++i) {
        a8[2 * i]     = __hip_atomic_load(pr + i * 8,     __ATOMIC_RELAXED,
                                          __HIP_MEMORY_SCOPE_AGENT);
        a8[2 * i + 1] = __hip_atomic_load(pr + i * 8 + 1, __ATOMIC_RELAXED,
                                          __HIP_MEMORY_SCOPE_AGENT);
      }
    }
    // prefetch next step's proj alongside (plain cached loads; proj is read-only)
    uint2 pjn[4];
    {
      int sn = (s < 511) ? s + 1 : 511;
      int tn = d ? 511 - sn : sn;
#pragma unroll
      for (int r = 0; r < 4; ++r)
        pjn[r] = *(const uint2*)(proj + ((size_t)tn * 64 + bbase + rowsel * 4 + r) * 2048
                                 + d * 1024 + (size_t)jlocal * 4);
    }

    // 3) acc = proj + bias
    floatx4 acc[4];
#pragma unroll
    for (int r = 0; r < 4; ++r) {
      union { uint2 u; f16 h[4]; } cv; cv.u = pj[r];
      acc[0][r] = (float)cv.h[0] + bias[0];
      acc[1][r] = (float)cv.h[1] + bias[1];
      acc[2][r] = (float)cv.h[2] + bias[2];
      acc[3][r] = (float)cv.h[3] + bias[3];
    }

    // 4) own-half MFMA from LDS (parity (s&1)^1), swizzled; static wreg idx
    {
      const int rb = ((s & 1) ^ 1) * 4096;
      const int swz = (bA & 7) << 4;
#pragma unroll
      for (int i = 0; i < 4; ++i) {
        uint4 a4o = *(const uint4*)(Hl + rb + ((bA * 256 + i * 64 + rowsel * 16) ^ swz));
        half8 av = __builtin_bit_cast(half8, a4o);
#pragma unroll
        for (int g = 0; g < 4; ++g)
          acc[g] = __builtin_amdgcn_mfma_f32_16x16x32_f16(av, wreg[g][(OWNBASE >> 5) + i],
                                                          acc[g], 0, 0, 0);
      }
    }

    // 5) peer-half MFMA (waits on a8); static wreg idx
#pragma unroll
    for (int i = 0; i < 4; ++i) {
      union { struct { u64 lo, hi; } w; half8 h; } fr;
      fr.w.lo = a8[2 * i]; fr.w.hi = a8[2 * i + 1];
#pragma unroll
      for (int g = 0; g < 4; ++g)
        acc[g] = __builtin_amdgcn_mfma_f32_16x16x32_f16(fr.h, wreg[g][(PEERBASE >> 5) + i],
                                                        acc[g], 0, 0, 0);
    }

    // 6) gates -> h, c
    const int wslot = d ? 512 - s : s + 1;
    float hvv[4];
    f16 hhv[4];
#pragma unroll
    for (int r = 0; r < 4; ++r) {
      float iv = sigf(acc[0][r]);
      float fv = sigf(acc[1][r]);
      float gv = tanhf_(acc[2][r]);
      float ov = sigf(acc[3][r]);
      cst[r] = fv * cst[r] + iv * gv;
      hvv[r] = ov * tanhf_(cst[r]);
      hhv[r] = (f16)hvv[r];
    }

    // 7) stores: LDS own-half (parity s&1, swizzled) + ring own chunk via
    //    relaxed agent atomic ushort stores (peer-visible at MALL; = h0 output)
    {
      char* wbuf = Hl + (s & 1) * 4096;
#pragma unroll
      for (int r = 0; r < 4; ++r) {
        int row = rowsel * 4 + r;
        *(f16*)(wbuf + ((row * 256 + klocal * 2) ^ ((row & 7) << 4))) = hhv[r];
        __hip_atomic_store(
            (unsigned short*)(ring + ((size_t)wslot * 64 + bbase + row) * 512
                              + d * 256 + jlocal),
            __builtin_bit_cast(unsigned short, hhv[r]),
            __ATOMIC_RELAXED, __HIP_MEMORY_SCOPE_AGENT);
      }
    }
    if (LAYER == 1 && s == 511) {
#pragma unroll
      for (int r = 0; r < 4; ++r)
        finalh[(size_t)(d * 64 + bbase + rowsel * 4 + r) * 256 + jlocal] = hvv[r];
    }

    // 8) barrier (pre-barrier vmcnt(0) drains every wave's atomic stores to
    //    MALL), then tid0 publishes with a relaxed atomic store (no release).
    __syncthreads();
    if (tid == 0)
      __hip_atomic_store(flagOwn, (unsigned)(s + 2), __ATOMIC_RELAXED,
                         __HIP_MEMORY_SCOPE_AGENT);

#pragma unroll
    for (int r = 0; r < 4; ++r) pj[r] = pjn[r];
  }
}

template<int LAYER>
__global__ __launch_bounds__(512, 2)
void k_scan(const f16* __restrict__ proj, const f16* __restrict__ whh,
            const float* __restrict__ bias_f, const float* __restrict__ bias_b,
            f16* ring, float* __restrict__ finalh, unsigned* ctr) {
  __shared__ __align__(16) char Hl[8192];  // 2 x [16 rows][128 cols] fp16, XOR-swizzled
  if ((blockIdx.x >> 3) == 0)
    scan_body<LAYER, 0>(proj, whh, bias_f, bias_b, ring, finalh, ctr, Hl);
  else
    scan_body<LAYER, 128>(proj, whh, bias_f, bias_b, ring, finalh, ctr, Hl);
}

// ---------------- final linear ----------------
__global__ void k_final(const float* __restrict__ fh, const float* __restrict__ wlin,
                        const float* __restrict__ blin, float* __restrict__ out) {
  int tid = threadIdx.x;
  int b = tid >> 2, part = tid & 3;
  float sum = 0.f;
#pragma unroll 4
  for (int jj = 0; jj < 128; ++jj) {
    int j = part * 128 + jj;
    float lastv = (j < 256) ? fh[b * 256 + j] : fh[(64 + b) * 256 + (j - 256)];
    sum += lastv * wlin[j];
  }
  sum += __shfl_xor(sum, 1);
  sum += __shfl_xor(sum, 2);
  if (part == 0) out[b] = sum + blin[0];
}

// ---------------- host ----------------
extern "C" void kernel_launch(void* const* d_in, const int* in_sizes, int n_in,
                              void* d_out, int out_size, void* d_ws, size_t ws_size,
                              hipStream_t stream) {
  const int*   x     = (const int*)  d_in[0];
  const float* embed = (const float*)d_in[1];
  const float* wih0f = (const float*)d_in[2];
  const float* whh0f = (const float*)d_in[3];
  const float* b0f   = (const float*)d_in[4];
  const float* wih0b = (const float*)d_in[5];
  const float* whh0b = (const float*)d_in[6];
  const float* b0b   = (const float*)d_in[7];
  const float* wih1f = (const float*)d_in[8];
  const float* whh1f = (const float*)d_in[9];
  const float* b1f   = (const float*)d_in[10];
  const float* wih1b = (const float*)d_in[11];
  const float* whh1b = (const float*)d_in[12];
  const float* b1b   = (const float*)d_in[13];
  const float* wlin  = (const float*)d_in[14];
  const float* blin  = (const float*)d_in[15];

  char* ws = (char*)d_ws;
  size_t off = 0;
  auto alloc = [&](size_t bytes) {
    char* p = ws + off;
    off = (off + bytes + 511) & ~(size_t)511;
    return p;
  };
  f16* embed16 = (f16*)alloc((size_t)50000 * 256 * 2);
  f16* wih0_16 = (f16*)alloc((size_t)2048 * 256 * 2);
  f16* wih1_16 = (f16*)alloc((size_t)2048 * 512 * 2);
  f16* whh0_16 = (f16*)alloc((size_t)2 * 1024 * 256 * 2);
  f16* whh1_16 = (f16*)alloc((size_t)2 * 1024 * 256 * 2);
  f16* proj    = (f16*)alloc((size_t)32768 * 2048 * 2);
  f16* ring    = (f16*)alloc((size_t)514 * 64 * 512 * 2);  // exchange ring; slots 1..512 = h0
  float* fh    = (float*)alloc((size_t)2 * 64 * 256 * 4);
  unsigned* ctr = (unsigned*)alloc((size_t)8 * 64 * 4);

  if (off > ws_size) {
    hipMemsetAsync(d_out, 0, (size_t)out_size * 4, stream);
    return;
  }

  k_cvt_embed<<<(12800000 / 8 + 255) / 256, 256, 0, stream>>>(embed, embed16, 12800000 / 8);
  k_cvt_wih<<<(2048 * 256 + 255) / 256, 256, 0, stream>>>(wih0f, wih0b, wih0_16, 256, 8, 2048 * 256);
  k_cvt_wih<<<(2048 * 512 + 255) / 256, 256, 0, stream>>>(wih1f, wih1b, wih1_16, 512, 9, 2048 * 512);
  k_cvt_whh<<<(524288 + 255) / 256, 256, 0, stream>>>(whh0f, whh0b, whh0_16);
  k_cvt_whh<<<(524288 + 255) / 256, 256, 0, stream>>>(whh1f, whh1b, whh1_16);

  // layer 0 input projection: [32768,256] x [2048,256]^T -> proj
  k_gemm<256, true><<<4096, 256, 0, stream>>>(embed16, wih0_16, x, proj);
  hipMemsetAsync(ctr, 0, (size_t)8 * 64 * 4, stream);
  k_scan<0><<<16, 512, 0, stream>>>(proj, whh0_16, b0f, b0b, ring, nullptr, ctr);

  // layer 1 input projection: A = ring slots 1..512 ([32768,512]), B = wih1
  k_gemm<512, false><<<4096, 256, 0, stream>>>(ring + 32768, wih1_16, nullptr, proj);
  hipMemsetAsync(ctr, 0, (size_t)8 * 64 * 4, stream);
  k_scan<1><<<16, 512, 0, stream>>>(proj, whh1_16, b1f, b1b, ring, fh, ctr);

  k_final<<<1, 256, 0, stream>>>(fh, wlin, blin, (float*)d_out);
}